// Round 12
// baseline (487.396 us; speedup 1.0000x reference)
//
#include <hip/hip_runtime.h>
#include <hip/hip_bf16.h>

typedef short bf16x8 __attribute__((ext_vector_type(8)));   // 8 bf16 in 4 VGPRs
typedef float f32x4  __attribute__((ext_vector_type(4)));

constexpr int B = 8, T = 10, F = 64, CO = 256;
constexpr long IMGPIX      = 48 * 48;                // 2304
constexpr long STATE_ELEMS = (long)B * IMGPIX * F;   // 1,179,648
constexpr long GX_IMG      = IMGPIX * 256;           // elems per image slab
constexpr float BN_INVN    = 1.0f / (float)(B * T * IMGPIX);

__device__ __forceinline__ float  b2f(ushort u) { return __uint_as_float(((unsigned)u) << 16); }
__device__ __forceinline__ ushort f2b(float f) {
    unsigned x = __float_as_uint(f);
    return (ushort)((x + 0x7fffu + ((x >> 16) & 1u)) >> 16);   // RNE
}
__device__ __forceinline__ float hsig(float x) { return fminf(fmaxf(0.2f * x + 0.5f, 0.f), 1.f); }
__device__ __forceinline__ float tanh_f(float v) {
    return 1.f - 2.f / (__expf(2.f * v) + 1.f);    // exact at +/-inf, ~1e-6 err
}

union V16 { uint4 u; bf16x8 b; };

// ---------------------------------------------------------------------------
// Batched input-to-gate conv (time-independent): gx = bf16(conv3x3(in,Wx)+bias).
// Grid = 7680 (80 imgs x 48 rows x 2 halves); N-split + K-split geometry.
// ---------------------------------------------------------------------------
template<int CIN, int CPAD, bool BNIN>
__global__ __launch_bounds__(256, 3) void conv_gates(
    const ushort* __restrict__ in,      // [80][2304][CIN] bf16
    const ushort* __restrict__ Wsw,     // [16 ntile][KS][64][8] bf16
    const float*  __restrict__ bias,    // (256)
    ushort* __restrict__ gx,            // [80][2304][256] bf16
    int permute,
    const float* __restrict__ stats,
    const float* __restrict__ gamma,
    const float* __restrict__ beta)
{
    constexpr int K   = 9 * CIN;
    constexpr int KS  = (K + 31) / 32;
    constexpr int KSH = (KS + 1) / 2;
    constexpr int KP  = KS * 32;
    constexpr int PATCHB = 3 * 50 * CPAD * 2;
    constexpr int GBUFB  = 48 * 132 * 4;             // 25,344
    constexpr int SMEMB  = PATCHB > GBUFB ? PATCHB : GBUFB;
    __shared__ __align__(16) unsigned char smem[SMEMB];
    __shared__ float bnsc[64], bnsh[64];

    const int bid = blockIdx.x;
    const int img_in = bid / 96;
    const int rem = bid % 96;
    const int y    = rem >> 1;
    const int half = rem & 1;
    const int tid = threadIdx.x, wid = tid >> 6, l = tid & 63;
    const int lm = l & 15, lk8 = (l >> 4) * 8;

    if constexpr (BNIN) {
        if (tid < 64) {
            const float mean = stats[tid] * BN_INVN;
            const float var  = stats[64 + tid] * BN_INVN - mean * mean;
            const float sc   = gamma[tid] * rsqrtf(var + 1e-3f);
            bnsc[tid] = sc;
            bnsh[tid] = beta[tid] - mean * sc;
        }
        __syncthreads();
    }

    // ---- stage 3 x 50 x CIN patch (zero-padded), CPAD channel stride ----
    const ushort* aBase = in + (size_t)img_in * IMGPIX * CIN;
    constexpr int C8 = CIN / 8;
    for (int e = tid; e < 3 * 48 * C8; e += 256) {
        const int r = e / (48 * C8), qq = e % (48 * C8);
        const int col = qq / C8, ci0 = (qq % C8) * 8;
        const int gy = y + r - 1;
        uint4 v = make_uint4(0, 0, 0, 0);
        if (gy >= 0 && gy < 48) {
            v = *(const uint4*)(aBase + ((size_t)gy * 48 + col) * CIN + ci0);
            if constexpr (BNIN) {      // BN only on real pixels; padding stays 0
                ushort* u = (ushort*)&v;
#pragma unroll
                for (int j = 0; j < 8; ++j)
                    u[j] = f2b(b2f(u[j]) * bnsc[ci0 + j] + bnsh[ci0 + j]);
            }
        }
        *(uint4*)(smem + ((r * 50 + col + 1) * CPAD + ci0) * 2) = v;
    }
    for (int e = tid; e < 3 * 2 * C8; e += 256) {             // pad cols 0, 49
        const int r = e / (2 * C8), qq = e % (2 * C8);
        const int dc = (qq / C8) ? 49 : 0, ci0 = (qq % C8) * 8;
        *(uint4*)(smem + ((r * 50 + dc) * CPAD + ci0) * 2) = make_uint4(0, 0, 0, 0);
    }
    __syncthreads();

    const int q      = 2 * half + (wid & 1);
    const int kshard = wid >> 1;
    f32x4 acc[3][4] = {};

#pragma unroll
    for (int ksl = 0; ksl < KSH; ++ksl) {
        const int ks = 2 * ksl + kshard;
        if (ks < KS) {
            V16 bf[4];
#pragma unroll
            for (int nr = 0; nr < 4; ++nr) {
                const int ntile = nr * 4 + q;
                bf[nr].u = *(const uint4*)(Wsw + ((size_t)((ntile * KS + ks) * 64) + l) * 8);
            }
            V16 af[3];
#pragma unroll
            for (int m = 0; m < 3; ++m) {
                const int k   = ks * 32 + lk8;
                const int tap = k / CIN, ci0 = k % CIN;
                const int ky  = tap / 3, kx = tap - 3 * (tap / 3);
                const int c   = m * 16 + lm + kx;
                uint4 v = *(const uint4*)(smem + ((ky * 50 + c) * CPAD + ci0) * 2);
                if (KP > K && ks == KS - 1 && k >= K) v = make_uint4(0, 0, 0, 0);
                af[m].u = v;
            }
#pragma unroll
            for (int m = 0; m < 3; ++m)
#pragma unroll
                for (int nr = 0; nr < 4; ++nr)
                    acc[m][nr] = __builtin_amdgcn_mfma_f32_16x16x32_bf16(
                        af[m].b, bf[nr].b, acc[m][nr], 0, 0, 0);
        }
    }

    // ---- combine K-shards in LDS, write gx (+bias) as bf16 uint4 chunks ----
    __syncthreads();
    float* gbuf = (float*)smem;            // [48][132]
    const int fl = (q & 1) * 16 + lm;
    if (kshard == 0) {
#pragma unroll
        for (int nr = 0; nr < 4; ++nr)
#pragma unroll
            for (int m = 0; m < 3; ++m)
#pragma unroll
                for (int r = 0; r < 4; ++r) {
                    const int pixel = m * 16 + (l >> 4) * 4 + r;
                    gbuf[pixel * 132 + nr * 32 + fl] = acc[m][nr][r];
                }
    }
    __syncthreads();
    if (kshard == 1) {
#pragma unroll
        for (int nr = 0; nr < 4; ++nr)
#pragma unroll
            for (int m = 0; m < 3; ++m)
#pragma unroll
                for (int r = 0; r < 4; ++r) {
                    const int pixel = m * 16 + (l >> 4) * 4 + r;
                    gbuf[pixel * 132 + nr * 32 + fl] += acc[m][nr][r];
                }
    }
    __syncthreads();

    const long slab = permute ? (long)(img_in % 10) * 8 + img_in / 10 : (long)img_in;
    ushort* gxp = gx + slab * GX_IMG + (long)y * 48 * 256;
#pragma unroll
    for (int it = 0; it < 3; ++it) {                 // 768 chunks of 8 channels
        const int idx = it * 256 + tid;
        const int p = idx >> 4, run = idx & 15;
        const int c0 = run * 8;                       // within block's 128 (same nr)
        const int nr = c0 >> 5;
        const int ch0 = nr * 64 + half * 32 + (c0 & 31);
        ushort o[8];
#pragma unroll
        for (int j = 0; j < 8; ++j)
            o[j] = f2b(gbuf[p * 132 + c0 + j] + bias[ch0 + j]);
        *(uint4*)(gxp + p * 256 + ch0) = *(const uint4*)o;
    }
}

// ---------------------------------------------------------------------------
// Serial recurrent step: g = gx(bf16) + conv3x3(h_prev, Wh); LSTM update.
// Grid = 768 (img x row x half); K = 576, KS = 18.  gx prefetched to regs
// before staging so its HBM latency hides under staging + MFMA.
// ---------------------------------------------------------------------------
template<bool FIRST, bool STATS, bool OUT>
__global__ __launch_bounds__(256, 3) void rec_step(
    const ushort* __restrict__ gx,      // this t's slab: [8][2304][256] bf16
    const ushort* __restrict__ hIn,     // (8,2304,64) bf16
    const ushort* __restrict__ Wsw,     // [16][18][64][8]
    float*  __restrict__ cState,
    ushort* __restrict__ hOut,
    ushort* __restrict__ seqOut,        // STATS only
    float*  __restrict__ stats,
    float*  __restrict__ outF)          // OUT only
{
    constexpr int CIN = 64, CPAD = 72, KS = 18, KSH = 9;
    constexpr int SMEMB = 26368;        // gbuf 25344 + sred 1024 > patch 21600
    __shared__ __align__(16) unsigned char smem[SMEMB];

    const int bid = blockIdx.x;
    const int img = bid / 96;
    const int rem = bid % 96;
    const int y    = rem >> 1;
    const int half = rem & 1;
    const int tid = threadIdx.x, wid = tid >> 6, l = tid & 63;
    const int lm = l & 15, lk8 = (l >> 4) * 8;

    // ---- early gx prefetch into registers (consumed in the epilogue) ----
    const ushort* gxrow = gx + ((size_t)img * IMGPIX + (size_t)y * 48) * 256;
    ushort gxv[24];
#pragma unroll
    for (int it = 0; it < 6; ++it) {
        const int idx = it * 256 + tid;
        const int p = idx >> 5, fr = idx & 31;
        const int chb = half * 32 + fr;
#pragma unroll
        for (int g = 0; g < 4; ++g)
            gxv[it * 4 + g] = gxrow[p * 256 + g * 64 + chb];
    }

    // ---- stage 3 x 50 x 64 h patch ----
    const ushort* bBase = hIn + (size_t)img * IMGPIX * 64;
    for (int e = tid; e < 3 * 48 * 8; e += 256) {
        const int r = e / (48 * 8), qq = e % (48 * 8);
        const int col = qq / 8, ci0 = (qq % 8) * 8;
        uint4 v = make_uint4(0, 0, 0, 0);
        if constexpr (!FIRST) {
            const int gy = y + r - 1;
            if (gy >= 0 && gy < 48)
                v = *(const uint4*)(bBase + ((size_t)gy * 48 + col) * 64 + ci0);
        }
        *(uint4*)(smem + ((r * 50 + col + 1) * CPAD + ci0) * 2) = v;
    }
    for (int e = tid; e < 3 * 2 * 8; e += 256) {              // pad cols 0, 49
        const int r = e / 16, qq = e % 16;
        const int dc = (qq / 8) ? 49 : 0, ci0 = (qq % 8) * 8;
        *(uint4*)(smem + ((r * 50 + dc) * CPAD + ci0) * 2) = make_uint4(0, 0, 0, 0);
    }
    __syncthreads();

    const int q      = 2 * half + (wid & 1);
    const int kshard = wid >> 1;
    f32x4 acc[3][4] = {};

#pragma unroll
    for (int ksl = 0; ksl < KSH; ++ksl) {
        const int ks = 2 * ksl + kshard;
        V16 bf[4];
#pragma unroll
        for (int nr = 0; nr < 4; ++nr) {
            const int ntile = nr * 4 + q;
            bf[nr].u = *(const uint4*)(Wsw + ((size_t)((ntile * KS + ks) * 64) + l) * 8);
        }
        V16 af[3];
#pragma unroll
        for (int m = 0; m < 3; ++m) {
            const int k   = ks * 32 + lk8;
            const int tap = k / CIN, ci0 = k % CIN;
            const int ky  = tap / 3, kx = tap - 3 * (tap / 3);
            const int c   = m * 16 + lm + kx;
            af[m].u = *(const uint4*)(smem + ((ky * 50 + c) * CPAD + ci0) * 2);
        }
#pragma unroll
        for (int m = 0; m < 3; ++m)
#pragma unroll
            for (int nr = 0; nr < 4; ++nr)
                acc[m][nr] = __builtin_amdgcn_mfma_f32_16x16x32_bf16(
                    af[m].b, bf[nr].b, acc[m][nr], 0, 0, 0);
    }

    // ---- combine K-shards, LSTM update ----
    __syncthreads();
    float* gbuf = (float*)smem;            // [48][132]
    float* sred = (float*)(smem + 25344);  // [4][2][32]
    const int fl = (q & 1) * 16 + lm;
    if (kshard == 0) {
#pragma unroll
        for (int nr = 0; nr < 4; ++nr)
#pragma unroll
            for (int m = 0; m < 3; ++m)
#pragma unroll
                for (int r = 0; r < 4; ++r) {
                    const int pixel = m * 16 + (l >> 4) * 4 + r;
                    gbuf[pixel * 132 + nr * 32 + fl] = acc[m][nr][r];
                }
    }
    __syncthreads();
    if (kshard == 1) {
#pragma unroll
        for (int nr = 0; nr < 4; ++nr)
#pragma unroll
            for (int m = 0; m < 3; ++m)
#pragma unroll
                for (int r = 0; r < 4; ++r) {
                    const int pixel = m * 16 + (l >> 4) * 4 + r;
                    gbuf[pixel * 132 + nr * 32 + fl] += acc[m][nr][r];
                }
    }
    __syncthreads();

    float s1 = 0.f, s2 = 0.f;
    const size_t rowBase = (size_t)img * IMGPIX + (size_t)y * 48;
#pragma unroll
    for (int it = 0; it < 6; ++it) {
        const int idx = it * 256 + tid;
        const int p = idx >> 5, fr = idx & 31;
        const int chb = half * 32 + fr;
        const float gi = gbuf[p * 132 +       fr] + b2f(gxv[it * 4 + 0]);
        const float gf = gbuf[p * 132 +  32 + fr] + b2f(gxv[it * 4 + 1]);
        const float gc = gbuf[p * 132 +  64 + fr] + b2f(gxv[it * 4 + 2]);
        const float go = gbuf[p * 132 +  96 + fr] + b2f(gxv[it * 4 + 3]);
        const size_t off = (rowBase + p) * 64 + chb;
        const float cold = FIRST ? 0.f : cState[off];
        const float cn = hsig(gf) * cold + hsig(gi) * tanh_f(gc);
        const float hn = hsig(go) * tanh_f(cn);
        cState[off] = cn;
        hOut[off]   = f2b(hn);
        if constexpr (STATS) { seqOut[off] = f2b(hn); s1 += hn; s2 += hn * hn; }
        if constexpr (OUT)   { outF[off] = hn; outF[STATE_ELEMS + off] = cn; }
    }

    if constexpr (STATS) {
        s1 += __shfl_xor(s1, 32);
        s2 += __shfl_xor(s2, 32);
        if (l < 32) { sred[wid * 64 + l] = s1; sred[wid * 64 + 32 + l] = s2; }
        __syncthreads();
        if (tid < 64) {
            const int kind = tid >> 5, fr = tid & 31;
            const float v = sred[kind * 32 + fr] + sred[64 + kind * 32 + fr]
                          + sred[128 + kind * 32 + fr] + sred[192 + kind * 32 + fr];
            atomicAdd(&stats[kind * 64 + half * 32 + fr], v);
        }
    }
}

// ---------------------------------------------------------------------------
// Prep: cast x -> bf16; build 4 swizzled weight buffers; zero stats.
// ---------------------------------------------------------------------------
__device__ __forceinline__ ushort swz_w(
    const float* __restrict__ W, int CIN, int KS, int idx)
{
    const int K = 9 * CIN;
    const int j = idx & 7, lw = (idx >> 3) & 63, rest = idx >> 9;
    const int ks = rest % KS, ntile = rest / KS;
    const int n = ntile * 16 + (lw & 15);
    const int k = ks * 32 + ((lw >> 4) & 3) * 8 + j;
    if (k >= K) return (ushort)0;
    const int tap = k / CIN, ci = k % CIN;
    return f2b(W[((size_t)tap * CIN + ci) * CO + n]);
}

__global__ __launch_bounds__(256) void prep_kernel(
    const float* __restrict__ x,
    const float* __restrict__ Wx1, const float* __restrict__ Wh1,
    const float* __restrict__ Wx2, const float* __restrict__ Wh2,
    ushort* __restrict__ xb,
    ushort* __restrict__ wx1, ushort* __restrict__ wh1,
    ushort* __restrict__ wx2, ushort* __restrict__ wh2,
    float* __restrict__ stats)
{
    constexpr int N0 = 368640;          // x elems / 8
    constexpr int N1 = 16 * 5 * 512;    // 40,960   (K=144 -> KS=5)
    constexpr int N2 = 16 * 18 * 512;   // 147,456  (K=576 -> KS=18)
    const int gid = blockIdx.x * 256 + threadIdx.x;
    if (gid < N0) {
        const float4 a = ((const float4*)x)[(size_t)gid * 2];
        const float4 b = ((const float4*)x)[(size_t)gid * 2 + 1];
        ushort o[8] = { f2b(a.x), f2b(a.y), f2b(a.z), f2b(a.w),
                        f2b(b.x), f2b(b.y), f2b(b.z), f2b(b.w) };
        *(uint4*)(xb + (size_t)gid * 8) = *(const uint4*)o;
    } else if (gid < N0 + N1) {
        wx1[gid - N0] = swz_w(Wx1, 16, 5, gid - N0);
    } else if (gid < N0 + N1 + N2) {
        wh1[gid - N0 - N1] = swz_w(Wh1, 64, 18, gid - N0 - N1);
    } else if (gid < N0 + N1 + 2 * N2) {
        wx2[gid - N0 - N1 - N2] = swz_w(Wx2, 64, 18, gid - N0 - N1 - N2);
    } else if (gid < N0 + N1 + 3 * N2) {
        wh2[gid - N0 - N1 - 2 * N2] = swz_w(Wh2, 64, 18, gid - N0 - N1 - 2 * N2);
    } else if (gid < N0 + N1 + 3 * N2 + 128) {
        stats[gid - N0 - N1 - 3 * N2] = 0.f;
    }
}

// ---------------------------------------------------------------------------
extern "C" void kernel_launch(void* const* d_in, const int* in_sizes, int n_in,
                              void* d_out, int out_size, void* d_ws, size_t ws_size,
                              hipStream_t stream)
{
    const float* x      = (const float*)d_in[0];
    const float* Wx1    = (const float*)d_in[1];
    const float* Wh1    = (const float*)d_in[2];
    const float* b1     = (const float*)d_in[3];
    const float* gamma1 = (const float*)d_in[4];
    const float* beta1  = (const float*)d_in[5];
    const float* Wx2    = (const float*)d_in[6];
    const float* Wh2    = (const float*)d_in[7];
    const float* b2     = (const float*)d_in[8];

    // workspace layout (bytes): ~146 MB of the 256 MiB ws
    unsigned char* w = (unsigned char*)d_ws;
    ushort* gx   = (ushort*)w;  w += 94371840;   // [80][2304][256] bf16 (reused L1/L2)
    ushort* seq1 = (ushort*)w;  w += 23592960;   // [80][2304][64] bf16 (t-major)
    ushort* xb   = (ushort*)w;  w += 5898240;    // (B,T,2304,16) bf16
    ushort* wx1  = (ushort*)w;  w += 81920;
    ushort* wh1  = (ushort*)w;  w += 294912;
    ushort* wx2  = (ushort*)w;  w += 294912;
    ushort* wh2  = (ushort*)w;  w += 294912;
    ushort* hb1a = (ushort*)w;  w += 2359296;
    ushort* hb1b = (ushort*)w;  w += 2359296;
    ushort* hb2a = (ushort*)w;  w += 2359296;
    ushort* hb2b = (ushort*)w;  w += 2359296;
    float*  c1   = (float*)w;   w += 4718592;
    float*  c2   = (float*)w;   w += 4718592;
    float*  stats = (float*)w;  w += 512;

    prep_kernel<<<3329, 256, 0, stream>>>(x, Wx1, Wh1, Wx2, Wh2,
                                          xb, wx1, wh1, wx2, wh2, stats);

    // ----- layer 1 -----
    conv_gates<16, 24, false><<<7680, 256, 0, stream>>>(
        xb, wx1, b1, gx, 1, nullptr, nullptr, nullptr);

    ushort* hp1[2] = { hb1a, hb1b };
    rec_step<true, true, false><<<768, 256, 0, stream>>>(
        gx, hp1[0], wh1, c1, hp1[1], seq1, stats, nullptr);
    for (int t = 1; t < 9; ++t)
        rec_step<false, true, false><<<768, 256, 0, stream>>>(
            gx + (size_t)t * 8 * GX_IMG, hp1[t & 1], wh1, c1, hp1[(t + 1) & 1],
            seq1 + (size_t)t * STATE_ELEMS, stats, nullptr);
    rec_step<false, true, true><<<768, 256, 0, stream>>>(
        gx + (size_t)9 * 8 * GX_IMG, hp1[1], wh1, c1, hp1[0],
        seq1 + (size_t)9 * STATE_ELEMS, stats, (float*)d_out);

    // ----- layer 2 -----
    conv_gates<64, 72, true><<<7680, 256, 0, stream>>>(
        seq1, wx2, b2, gx, 0, stats, gamma1, beta1);

    ushort* hp2[2] = { hb2a, hb2b };
    rec_step<true, false, false><<<768, 256, 0, stream>>>(
        gx, hp2[0], wh2, c2, hp2[1], nullptr, stats, nullptr);
    for (int t = 1; t < 9; ++t)
        rec_step<false, false, false><<<768, 256, 0, stream>>>(
            gx + (size_t)t * 8 * GX_IMG, hp2[t & 1], wh2, c2, hp2[(t + 1) & 1],
            nullptr, stats, nullptr);
    rec_step<false, false, true><<<768, 256, 0, stream>>>(
        gx + (size_t)9 * 8 * GX_IMG, hp2[1], wh2, c2, hp2[0],
        nullptr, stats, (float*)d_out + 2 * STATE_ELEMS);
}

// Round 13
// 413.414 us; speedup vs baseline: 1.1790x; 1.1790x over previous
//
#include <hip/hip_runtime.h>
#include <hip/hip_bf16.h>

typedef short bf16x8 __attribute__((ext_vector_type(8)));   // 8 bf16 in 4 VGPRs
typedef float f32x4  __attribute__((ext_vector_type(4)));

constexpr int B = 8, T = 10, F = 64, CO = 256;
constexpr long IMGPIX      = 48 * 48;                // 2304
constexpr long STATE_ELEMS = (long)B * IMGPIX * F;   // 1,179,648
constexpr float BN_INVN    = 1.0f / (float)(B * T * IMGPIX);

__device__ __forceinline__ float  b2f(ushort u) { return __uint_as_float(((unsigned)u) << 16); }
__device__ __forceinline__ ushort f2b(float f) {
    unsigned x = __float_as_uint(f);
    return (ushort)((x + 0x7fffu + ((x >> 16) & 1u)) >> 16);   // RNE
}
__device__ __forceinline__ float hsig(float x) { return fminf(fmaxf(0.2f * x + 0.5f, 0.f), 1.f); }
__device__ __forceinline__ float tanh_f(float v) {
    return 1.f - 2.f / (__expf(2.f * v) + 1.f);    // exact at +/-inf, ~1e-6 err
}

union V16 { uint4 u; bf16x8 b; };

// ---------------------------------------------------------------------------
// Fused ConvLSTM step (round-7 verified structure) + manual weight software
// pipeline: per ks iteration, the NEXT weight fragments are issued before the
// current LDS reads + 12 MFMAs, hiding the ~250-cycle L2 load latency that
// capped MfmaUtil at ~26%.  Grid = 768: (img, row y, channel-half).
// Wave wid: q = 2*half + (wid&1) -> f-channels [q*16,(q+1)*16); kshard=wid>>1
// takes ks = 2*ksl + kshard.  Partial sums combined in LDS, then the block
// does the LSTM gate update for its 32 f-channels.
// ---------------------------------------------------------------------------
template<int CIN_A, int CPAD, bool FIRST, bool STATS, bool BNIN, bool OUT>
__global__ __launch_bounds__(256, 3) void convlstm_step(
    const ushort* __restrict__ inA, long strideA,   // per-img stride (elements)
    const ushort* __restrict__ inB,                 // h_prev (B,2304,64) bf16
    const ushort* __restrict__ Wsw,                 // swizzled [ntile][KS][64][8]
    const float*  __restrict__ bias,                // (256)
    float*  __restrict__ cState,                    // (B,2304,64) f32 in place
    ushort* __restrict__ hOut,                      // (B,2304,64) bf16
    ushort* __restrict__ seqOut,                    // STATS only
    float*  __restrict__ stats,                     // [128]
    const float* __restrict__ gamma,
    const float* __restrict__ beta,
    float*  __restrict__ outF)                      // OUT only
{
    constexpr int CIN_TOT = CIN_A + 64;
    constexpr int K   = 9 * CIN_TOT;
    constexpr int KS  = (K + 31) / 32;
    constexpr int KSH = (KS + 1) / 2;
    constexpr int KP  = KS * 32;
    constexpr int PATCHB = 3 * 50 * CPAD * 2;
    constexpr int SMEMB  = PATCHB > 26368 ? PATCHB : 26368;  // gbuf 25344 + sred 1024
    __shared__ __align__(16) unsigned char smem[SMEMB];
    __shared__ float bnsc[64], bnsh[64];

    const int bid  = blockIdx.x;
    const int img  = bid / 96;
    const int rem  = bid % 96;
    const int y    = rem >> 1;
    const int half = rem & 1;
    const int tid = threadIdx.x, wid = tid >> 6, l = tid & 63;
    const int lm = l & 15, lk8 = (l >> 4) * 8;

    const int q      = 2 * half + (wid & 1);
    const int kshard = wid >> 1;

    // ---- weight preload for ks = kshard issued BEFORE staging (independent) ----
    V16 bf[4];
#pragma unroll
    for (int nr = 0; nr < 4; ++nr) {
        const int ntile = nr * 4 + q;
        bf[nr].u = *(const uint4*)(Wsw + ((size_t)((ntile * KS + kshard) * 64) + l) * 8);
    }

    if constexpr (BNIN) {
        if (tid < 64) {
            const float mean = stats[tid] * BN_INVN;
            const float var  = stats[64 + tid] * BN_INVN - mean * mean;
            const float sc   = gamma[tid] * rsqrtf(var + 1e-3f);
            bnsc[tid] = sc;
            bnsh[tid] = beta[tid] - mean * sc;
        }
        __syncthreads();
    }

    // ---- stage 3 x 50 x CIN_TOT patch (zero-padded), padded channel stride ----
    const ushort* aBase = inA + (size_t)img * strideA;
    const ushort* bBase = inB + (size_t)img * IMGPIX * 64;
    constexpr int CA8 = CIN_A / 8;
    for (int e = tid; e < 3 * 48 * CA8; e += 256) {           // x/seq channels
        const int r = e / (48 * CA8), qq = e % (48 * CA8);
        const int col = qq / CA8, ci0 = (qq % CA8) * 8;
        const int gy = y + r - 1;
        uint4 v = make_uint4(0, 0, 0, 0);
        if (gy >= 0 && gy < 48) {
            v = *(const uint4*)(aBase + ((size_t)gy * 48 + col) * CIN_A + ci0);
            if constexpr (BNIN) {      // BN only on real pixels; padding stays 0
                ushort* u = (ushort*)&v;
#pragma unroll
                for (int j = 0; j < 8; ++j)
                    u[j] = f2b(b2f(u[j]) * bnsc[ci0 + j] + bnsh[ci0 + j]);
            }
        }
        *(uint4*)(smem + ((r * 50 + col + 1) * CPAD + ci0) * 2) = v;
    }
    for (int e = tid; e < 3 * 48 * 8; e += 256) {             // h channels
        const int r = e / (48 * 8), qq = e % (48 * 8);
        const int col = qq / 8, ci0 = (qq % 8) * 8;
        uint4 v = make_uint4(0, 0, 0, 0);
        if constexpr (!FIRST) {
            const int gy = y + r - 1;
            if (gy >= 0 && gy < 48)
                v = *(const uint4*)(bBase + ((size_t)gy * 48 + col) * 64 + ci0);
        }
        *(uint4*)(smem + ((r * 50 + col + 1) * CPAD + CIN_A + ci0) * 2) = v;
    }
    constexpr int CT8 = CIN_TOT / 8;
    for (int e = tid; e < 3 * 2 * CT8; e += 256) {            // pad cols 0 and 49
        const int r = e / (2 * CT8), qq = e % (2 * CT8);
        const int dc = (qq / CT8) ? 49 : 0, ci0 = (qq % CT8) * 8;
        *(uint4*)(smem + ((r * 50 + dc) * CPAD + ci0) * 2) = make_uint4(0, 0, 0, 0);
    }
    __syncthreads();

    f32x4 acc[3][4] = {};

#pragma unroll
    for (int ksl = 0; ksl < KSH; ++ksl) {
        const int ks  = 2 * ksl + kshard;
        const int nks = ks + 2;
        // ---- issue NEXT iteration's weight loads first (latency hiding) ----
        V16 bfn[4];
        if (nks < KS) {
#pragma unroll
            for (int nr = 0; nr < 4; ++nr) {
                const int ntile = nr * 4 + q;
                bfn[nr].u = *(const uint4*)(Wsw + ((size_t)((ntile * KS + nks) * 64) + l) * 8);
            }
        }
        if (ks < KS) {
            V16 af[3];
#pragma unroll
            for (int m = 0; m < 3; ++m) {
                const int k   = ks * 32 + lk8;
                const int tap = k / CIN_TOT, ci0 = k % CIN_TOT;
                const int ky  = tap / 3, kx = tap - 3 * (tap / 3);
                const int c   = m * 16 + lm + kx;
                uint4 v = *(const uint4*)(smem + ((ky * 50 + c) * CPAD + ci0) * 2);
                if (KP > K && ks == KS - 1 && k >= K) v = make_uint4(0, 0, 0, 0);
                af[m].u = v;
            }
#pragma unroll
            for (int m = 0; m < 3; ++m)
#pragma unroll
                for (int nr = 0; nr < 4; ++nr)
                    acc[m][nr] = __builtin_amdgcn_mfma_f32_16x16x32_bf16(
                        af[m].b, bf[nr].b, acc[m][nr], 0, 0, 0);
        }
        if (nks < KS) {
#pragma unroll
            for (int nr = 0; nr < 4; ++nr) bf[nr] = bfn[nr];
        }
    }

    // ---- combine K-shards in LDS, then gate update ----
    __syncthreads();                       // patch region now dead
    float* gbuf = (float*)smem;            // [48][132] f32
    float* sred = (float*)(smem + 25344);  // [4][2][32] f32
    const int fl = (q & 1) * 16 + lm;      // f index within block's 32

    if (kshard == 0) {
#pragma unroll
        for (int nr = 0; nr < 4; ++nr) {
            const float bv = bias[nr * 64 + q * 16 + lm];
#pragma unroll
            for (int m = 0; m < 3; ++m)
#pragma unroll
                for (int r = 0; r < 4; ++r) {
                    const int pixel = m * 16 + (l >> 4) * 4 + r;
                    gbuf[pixel * 132 + nr * 32 + fl] = acc[m][nr][r] + bv;
                }
        }
    }
    __syncthreads();
    if (kshard == 1) {
#pragma unroll
        for (int nr = 0; nr < 4; ++nr)
#pragma unroll
            for (int m = 0; m < 3; ++m)
#pragma unroll
                for (int r = 0; r < 4; ++r) {
                    const int pixel = m * 16 + (l >> 4) * 4 + r;
                    gbuf[pixel * 132 + nr * 32 + fl] += acc[m][nr][r];
                }
    }
    __syncthreads();

    float s1 = 0.f, s2 = 0.f;
    const size_t rowBase = (size_t)img * IMGPIX + (size_t)y * 48;
#pragma unroll
    for (int it = 0; it < 6; ++it) {
        const int idx = it * 256 + tid;
        const int p = idx >> 5, fr = idx & 31;     // fr fixed per thread
        const float gi = gbuf[p * 132 + fr];
        const float gf = gbuf[p * 132 + 32 + fr];
        const float gc = gbuf[p * 132 + 64 + fr];
        const float go = gbuf[p * 132 + 96 + fr];
        const size_t off = (rowBase + p) * 64 + half * 32 + fr;
        const float cold = FIRST ? 0.f : cState[off];
        const float cn = hsig(gf) * cold + hsig(gi) * tanh_f(gc);
        const float hn = hsig(go) * tanh_f(cn);
        cState[off] = cn;
        hOut[off]   = f2b(hn);
        if constexpr (STATS) { seqOut[off] = f2b(hn); s1 += hn; s2 += hn * hn; }
        if constexpr (OUT)   { outF[off] = hn; outF[STATE_ELEMS + off] = cn; }
    }

    if constexpr (STATS) {
        s1 += __shfl_xor(s1, 32);
        s2 += __shfl_xor(s2, 32);
        if (l < 32) { sred[wid * 64 + l] = s1; sred[wid * 64 + 32 + l] = s2; }
        __syncthreads();
        if (tid < 64) {
            const int kind = tid >> 5, fr = tid & 31;
            const float v = sred[kind * 32 + fr] + sred[64 + kind * 32 + fr]
                          + sred[128 + kind * 32 + fr] + sred[192 + kind * 32 + fr];
            atomicAdd(&stats[kind * 64 + half * 32 + fr], v);
        }
    }
}

// ---------------------------------------------------------------------------
// One-shot prep: cast x to bf16, build both swizzled concat weights, zero stats.
// Weight layout: out[((ntile*KS+ks)*64+l)*8+j] = Wcat[k][n], n = ntile*16+(l&15),
// k = ks*32+((l>>4)&3)*8+j; Wcat k-order tap-major, ci = [x-ch | h-ch].
// ---------------------------------------------------------------------------
__device__ __forceinline__ ushort swz_elem(
    const float* __restrict__ Wx, const float* __restrict__ Wh,
    int CIN_A, int KS, int idx)
{
    const int K = 9 * (CIN_A + 64);
    const int j = idx & 7, lw = (idx >> 3) & 63, rest = idx >> 9;
    const int ks = rest % KS, ntile = rest / KS;
    const int n = ntile * 16 + (lw & 15);
    const int k = ks * 32 + ((lw >> 4) & 3) * 8 + j;
    if (k >= K) return (ushort)0;
    const int CT = CIN_A + 64;
    const int tap = k / CT, ci = k % CT;
    const float v = (ci < CIN_A) ? Wx[((size_t)tap * CIN_A + ci) * CO + n]
                                 : Wh[((size_t)tap * 64 + (ci - CIN_A)) * CO + n];
    return f2b(v);
}

__global__ __launch_bounds__(256) void prep_kernel(
    const float* __restrict__ x,
    const float* __restrict__ Wx1, const float* __restrict__ Wh1,
    const float* __restrict__ Wx2, const float* __restrict__ Wh2,
    ushort* __restrict__ xb, ushort* __restrict__ wc1, ushort* __restrict__ wc2,
    float* __restrict__ stats)
{
    constexpr int N0 = 368640;          // x: 2,949,120 elems / 8
    constexpr int N1 = 16 * 23 * 512;   // 188,416
    constexpr int N2 = 16 * 36 * 512;   // 294,912
    const int gid = blockIdx.x * 256 + threadIdx.x;
    if (gid < N0) {
        const float4 a = ((const float4*)x)[(size_t)gid * 2];
        const float4 b = ((const float4*)x)[(size_t)gid * 2 + 1];
        ushort o[8] = { f2b(a.x), f2b(a.y), f2b(a.z), f2b(a.w),
                        f2b(b.x), f2b(b.y), f2b(b.z), f2b(b.w) };
        *(uint4*)(xb + (size_t)gid * 8) = *(const uint4*)o;
    } else if (gid < N0 + N1) {
        wc1[gid - N0] = swz_elem(Wx1, Wh1, 16, 23, gid - N0);
    } else if (gid < N0 + N1 + N2) {
        wc2[gid - N0 - N1] = swz_elem(Wx2, Wh2, 64, 36, gid - N0 - N1);
    } else if (gid < N0 + N1 + N2 + 128) {
        stats[gid - N0 - N1 - N2] = 0.f;
    }
}

// ---------------------------------------------------------------------------
extern "C" void kernel_launch(void* const* d_in, const int* in_sizes, int n_in,
                              void* d_out, int out_size, void* d_ws, size_t ws_size,
                              hipStream_t stream)
{
    const float* x      = (const float*)d_in[0];
    const float* Wx1    = (const float*)d_in[1];
    const float* Wh1    = (const float*)d_in[2];
    const float* b1     = (const float*)d_in[3];
    const float* gamma1 = (const float*)d_in[4];
    const float* beta1  = (const float*)d_in[5];
    const float* Wx2    = (const float*)d_in[6];
    const float* Wh2    = (const float*)d_in[7];
    const float* b2     = (const float*)d_in[8];

    // workspace layout (bytes) -- ~49 MB of the 256 MB ws
    unsigned char* w = (unsigned char*)d_ws;
    ushort* seq1 = (ushort*)w;  w += 23592960;   // (T,B,2304,64) bf16
    ushort* xb   = (ushort*)w;  w += 5898240;    // (B,T,2304,16) bf16
    ushort* wc1  = (ushort*)w;  w += 376832;     // 16*23*512 u16
    ushort* wc2  = (ushort*)w;  w += 589824;     // 16*36*512 u16
    ushort* hb1a = (ushort*)w;  w += 2359296;
    ushort* hb1b = (ushort*)w;  w += 2359296;
    ushort* hb2a = (ushort*)w;  w += 2359296;
    ushort* hb2b = (ushort*)w;  w += 2359296;
    float*  c1   = (float*)w;   w += 4718592;
    float*  c2   = (float*)w;   w += 4718592;
    float*  stats = (float*)w;  w += 512;

    prep_kernel<<<3329, 256, 0, stream>>>(x, Wx1, Wh1, Wx2, Wh2, xb, wc1, wc2, stats);

    const long xStride = (long)T * IMGPIX * 16;
    ushort* hp1[2] = { hb1a, hb1b };

    // ----- layer 1 (STATS: accumulate BN sums; t=9 also writes d_out h1,c1) -----
    convlstm_step<16, 88, true, true, false, false><<<768, 256, 0, stream>>>(
        xb, xStride, hp1[0], wc1, b1, c1, hp1[1],
        seq1, stats, nullptr, nullptr, nullptr);
    for (int t = 1; t < 9; ++t)
        convlstm_step<16, 88, false, true, false, false><<<768, 256, 0, stream>>>(
            xb + (size_t)t * IMGPIX * 16, xStride, hp1[t & 1], wc1, b1, c1, hp1[(t + 1) & 1],
            seq1 + (size_t)t * STATE_ELEMS, stats, nullptr, nullptr, nullptr);
    convlstm_step<16, 88, false, true, false, true><<<768, 256, 0, stream>>>(
        xb + (size_t)9 * IMGPIX * 16, xStride, hp1[1], wc1, b1, c1, hp1[0],
        seq1 + (size_t)9 * STATE_ELEMS, stats, nullptr, nullptr, (float*)d_out);

    // ----- layer 2 (BNIN: normalize seq1 on the fly; t=9 writes d_out h2,c2) -----
    ushort* hp2[2] = { hb2a, hb2b };
    convlstm_step<64, 136, true, false, true, false><<<768, 256, 0, stream>>>(
        seq1, IMGPIX * 64, hp2[0], wc2, b2, c2, hp2[1],
        nullptr, stats, gamma1, beta1, nullptr);
    for (int t = 1; t < 9; ++t)
        convlstm_step<64, 136, false, false, true, false><<<768, 256, 0, stream>>>(
            seq1 + (size_t)t * STATE_ELEMS, IMGPIX * 64, hp2[t & 1], wc2, b2, c2, hp2[(t + 1) & 1],
            nullptr, stats, gamma1, beta1, nullptr);
    convlstm_step<64, 136, false, false, true, true><<<768, 256, 0, stream>>>(
        seq1 + (size_t)9 * STATE_ELEMS, IMGPIX * 64, hp2[1], wc2, b2, c2, hp2[0],
        nullptr, stats, gamma1, beta1, (float*)d_out + 2 * STATE_ELEMS);
}

// Round 14
// 413.065 us; speedup vs baseline: 1.1799x; 1.0008x over previous
//
#include <hip/hip_runtime.h>
#include <hip/hip_bf16.h>

typedef short bf16x8 __attribute__((ext_vector_type(8)));   // 8 bf16 in 4 VGPRs
typedef float f32x4  __attribute__((ext_vector_type(4)));

constexpr int B = 8, T = 10, F = 64, CO = 256;
constexpr long IMGPIX      = 48 * 48;                // 2304
constexpr long STATE_ELEMS = (long)B * IMGPIX * F;   // 1,179,648
constexpr float BN_INVN    = 1.0f / (float)(B * T * IMGPIX);

__device__ __forceinline__ float  b2f(ushort u) { return __uint_as_float(((unsigned)u) << 16); }
__device__ __forceinline__ ushort f2b(float f) {
    unsigned x = __float_as_uint(f);
    return (ushort)((x + 0x7fffu + ((x >> 16) & 1u)) >> 16);   // RNE
}
__device__ __forceinline__ float hsig(float x) { return fminf(fmaxf(0.2f * x + 0.5f, 0.f), 1.f); }
__device__ __forceinline__ float tanh_f(float v) {
    return 1.f - 2.f / (__expf(2.f * v) + 1.f);    // exact at +/-inf, ~1e-6 err
}

union V16 { uint4 u; bf16x8 b; };

// ---------------------------------------------------------------------------
// K-loop with segment-major weight order and STATIC A-addressing.
// k-order: [x-segment: taps 0..8 x CIN_A ch, zero-padded to KSX*32]
//          [h-segment: taps 0..8 x 64 ch (18 ks)]
// For 64-ch segments (h always; x too when CIN_A==64): tap = khs>>1 and
// ch = (khs&1)*32 are compile-time after unroll+KSHARD branch, so every
// ds_read_b128 is (smem + loop-invariant) + immediate.  Generic path only
// for L1's 5 x-segment iterations (CIN_A=16, with k>=144 tail clamp).
// ---------------------------------------------------------------------------
template<int CIN_A, int CPAD, int KSHARD>
__device__ __forceinline__ void mfma_loop(
    const unsigned char* __restrict__ smem,
    const unsigned char* __restrict__ pA,    // smem + (lm*CPAD + lk8)*2
    const ushort* __restrict__ Wsw,
    int q, int l, f32x4 (&acc)[3][4])
{
    constexpr int KX  = 9 * CIN_A;
    constexpr int KSX = (KX + 31) / 32;
    constexpr int KS  = KSX + 18;
    constexpr int ITERS = (KS - KSHARD + 1) / 2;
    const int lm  = l & 15;
    const int lk8 = (l >> 4) * 8;

#pragma unroll
    for (int ksl = 0; ksl < ITERS; ++ksl) {
        const int ks = 2 * ksl + KSHARD;          // folds under unroll
        V16 bf[4];
#pragma unroll
        for (int nr = 0; nr < 4; ++nr) {
            const int ntile = nr * 4 + q;
            bf[nr].u = *(const uint4*)(Wsw + ((size_t)((ntile * KS + ks) * 64) + l) * 8);
        }
        V16 af[3];
        if (CIN_A == 64 || ks >= KSX) {
            // ---- static 64-channel segment ----
            const int base_ch = (CIN_A == 64 && ks < KSX) ? 0 : CIN_A;
            const int khs     = (CIN_A == 64 && ks < KSX) ? ks : ks - KSX;
            const int tap = khs >> 1;
            const int ky = tap / 3, kx = tap - 3 * (tap / 3);
            const int ch = base_ch + (khs & 1) * 32;
#pragma unroll
            for (int m = 0; m < 3; ++m) {
                const int IMM = ((ky * 50 + kx + m * 16) * CPAD + ch) * 2;
                af[m].u = *(const uint4*)(pA + IMM);
            }
        } else {
            // ---- generic x-segment (L1, CIN_A=16; 5 iterations) ----
            const int k = ks * 32 + lk8;
            const bool valid = (k < KX);
            const int tap = valid ? (2 * ks + (lk8 >> 4)) : 0;   // k/16
            const int ky = tap / 3, kx = tap - 3 * (tap / 3);
            const int dci = (lk8 & 16) * 2;                      // ci0-lk8 = -(lk8&16)
#pragma unroll
            for (int m = 0; m < 3; ++m) {
                const int base = ((ky * 50 + kx + m * 16) * CPAD) * 2;
                uint4 v = *(const uint4*)(pA + (valid ? base - dci : 0));
                if (!valid) v = make_uint4(0, 0, 0, 0);
                af[m].u = v;
            }
        }
#pragma unroll
        for (int m = 0; m < 3; ++m)
#pragma unroll
            for (int nr = 0; nr < 4; ++nr)
                acc[m][nr] = __builtin_amdgcn_mfma_f32_16x16x32_bf16(
                    af[m].b, bf[nr].b, acc[m][nr], 0, 0, 0);
    }
}

// ---------------------------------------------------------------------------
// Fused ConvLSTM step (round-7 verified structure).  Grid = 768:
// (img, row y, channel-half).  Wave wid: q = 2*half+(wid&1); kshard = wid>>1.
// ---------------------------------------------------------------------------
template<int CIN_A, int CPAD, bool FIRST, bool STATS, bool BNIN, bool OUT>
__global__ __launch_bounds__(256, 3) void convlstm_step(
    const ushort* __restrict__ inA, long strideA,   // per-img stride (elements)
    const ushort* __restrict__ inB,                 // h_prev (B,2304,64) bf16
    const ushort* __restrict__ Wsw,                 // swizzled [ntile][KS][64][8]
    const float*  __restrict__ bias,                // (256)
    float*  __restrict__ cState,                    // (B,2304,64) f32 in place
    ushort* __restrict__ hOut,                      // (B,2304,64) bf16
    ushort* __restrict__ seqOut,                    // STATS only
    float*  __restrict__ stats,                     // [128]
    const float* __restrict__ gamma,
    const float* __restrict__ beta,
    float*  __restrict__ outF)                      // OUT only
{
    constexpr int CIN_TOT = CIN_A + 64;
    constexpr int PATCHB = 3 * 50 * CPAD * 2;
    constexpr int SMEMB  = PATCHB > 26368 ? PATCHB : 26368;  // gbuf 25344 + sred 1024
    __shared__ __align__(16) unsigned char smem[SMEMB];
    __shared__ float bnsc[64], bnsh[64];

    const int bid  = blockIdx.x;
    const int img  = bid / 96;
    const int rem  = bid % 96;
    const int y    = rem >> 1;
    const int half = rem & 1;
    const int tid = threadIdx.x, wid = tid >> 6, l = tid & 63;
    const int lm = l & 15, lk8 = (l >> 4) * 8;

    if constexpr (BNIN) {
        if (tid < 64) {
            const float mean = stats[tid] * BN_INVN;
            const float var  = stats[64 + tid] * BN_INVN - mean * mean;
            const float sc   = gamma[tid] * rsqrtf(var + 1e-3f);
            bnsc[tid] = sc;
            bnsh[tid] = beta[tid] - mean * sc;
        }
        __syncthreads();
    }

    // ---- stage 3 x 50 x CIN_TOT patch (zero-padded), padded channel stride ----
    const ushort* aBase = inA + (size_t)img * strideA;
    const ushort* bBase = inB + (size_t)img * IMGPIX * 64;
    constexpr int CA8 = CIN_A / 8;
    for (int e = tid; e < 3 * 48 * CA8; e += 256) {           // x/seq channels
        const int r = e / (48 * CA8), qq = e % (48 * CA8);
        const int col = qq / CA8, ci0 = (qq % CA8) * 8;
        const int gy = y + r - 1;
        uint4 v = make_uint4(0, 0, 0, 0);
        if (gy >= 0 && gy < 48) {
            v = *(const uint4*)(aBase + ((size_t)gy * 48 + col) * CIN_A + ci0);
            if constexpr (BNIN) {      // BN only on real pixels; padding stays 0
                ushort* u = (ushort*)&v;
#pragma unroll
                for (int j = 0; j < 8; ++j)
                    u[j] = f2b(b2f(u[j]) * bnsc[ci0 + j] + bnsh[ci0 + j]);
            }
        }
        *(uint4*)(smem + ((r * 50 + col + 1) * CPAD + ci0) * 2) = v;
    }
    for (int e = tid; e < 3 * 48 * 8; e += 256) {             // h channels
        const int r = e / (48 * 8), qq = e % (48 * 8);
        const int col = qq / 8, ci0 = (qq % 8) * 8;
        uint4 v = make_uint4(0, 0, 0, 0);
        if constexpr (!FIRST) {
            const int gy = y + r - 1;
            if (gy >= 0 && gy < 48)
                v = *(const uint4*)(bBase + ((size_t)gy * 48 + col) * 64 + ci0);
        }
        *(uint4*)(smem + ((r * 50 + col + 1) * CPAD + CIN_A + ci0) * 2) = v;
    }
    constexpr int CT8 = CIN_TOT / 8;
    for (int e = tid; e < 3 * 2 * CT8; e += 256) {            // pad cols 0 and 49
        const int r = e / (2 * CT8), qq = e % (2 * CT8);
        const int dc = (qq / CT8) ? 49 : 0, ci0 = (qq % CT8) * 8;
        *(uint4*)(smem + ((r * 50 + dc) * CPAD + ci0) * 2) = make_uint4(0, 0, 0, 0);
    }
    __syncthreads();

    const int q      = 2 * half + (wid & 1);
    const int kshard = wid >> 1;
    const unsigned char* pA = smem + (lm * CPAD + lk8) * 2;

    f32x4 acc[3][4] = {};
    if (kshard == 0) mfma_loop<CIN_A, CPAD, 0>(smem, pA, Wsw, q, l, acc);
    else             mfma_loop<CIN_A, CPAD, 1>(smem, pA, Wsw, q, l, acc);

    // ---- combine K-shards in LDS, then gate update ----
    __syncthreads();                       // patch region now dead
    float* gbuf = (float*)smem;            // [48][132] f32
    float* sred = (float*)(smem + 25344);  // [4][2][32] f32
    const int fl = (q & 1) * 16 + lm;      // f index within block's 32

    if (kshard == 0) {
#pragma unroll
        for (int nr = 0; nr < 4; ++nr) {
            const float bv = bias[nr * 64 + q * 16 + lm];
#pragma unroll
            for (int m = 0; m < 3; ++m)
#pragma unroll
                for (int r = 0; r < 4; ++r) {
                    const int pixel = m * 16 + (l >> 4) * 4 + r;
                    gbuf[pixel * 132 + nr * 32 + fl] = acc[m][nr][r] + bv;
                }
        }
    }
    __syncthreads();
    if (kshard == 1) {
#pragma unroll
        for (int nr = 0; nr < 4; ++nr)
#pragma unroll
            for (int m = 0; m < 3; ++m)
#pragma unroll
                for (int r = 0; r < 4; ++r) {
                    const int pixel = m * 16 + (l >> 4) * 4 + r;
                    gbuf[pixel * 132 + nr * 32 + fl] += acc[m][nr][r];
                }
    }
    __syncthreads();

    float s1 = 0.f, s2 = 0.f;
    const size_t rowBase = (size_t)img * IMGPIX + (size_t)y * 48;
#pragma unroll
    for (int it = 0; it < 6; ++it) {
        const int idx = it * 256 + tid;
        const int p = idx >> 5, fr = idx & 31;     // fr fixed per thread
        const float gi = gbuf[p * 132 + fr];
        const float gf = gbuf[p * 132 + 32 + fr];
        const float gc = gbuf[p * 132 + 64 + fr];
        const float go = gbuf[p * 132 + 96 + fr];
        const size_t off = (rowBase + p) * 64 + half * 32 + fr;
        const float cold = FIRST ? 0.f : cState[off];
        const float cn = hsig(gf) * cold + hsig(gi) * tanh_f(gc);
        const float hn = hsig(go) * tanh_f(cn);
        cState[off] = cn;
        hOut[off]   = f2b(hn);
        if constexpr (STATS) { seqOut[off] = f2b(hn); s1 += hn; s2 += hn * hn; }
        if constexpr (OUT)   { outF[off] = hn; outF[STATE_ELEMS + off] = cn; }
    }

    if constexpr (STATS) {
        s1 += __shfl_xor(s1, 32);
        s2 += __shfl_xor(s2, 32);
        if (l < 32) { sred[wid * 64 + l] = s1; sred[wid * 64 + 32 + l] = s2; }
        __syncthreads();
        if (tid < 64) {
            const int kind = tid >> 5, fr = tid & 31;
            const float v = sred[kind * 32 + fr] + sred[64 + kind * 32 + fr]
                          + sred[128 + kind * 32 + fr] + sred[192 + kind * 32 + fr];
            atomicAdd(&stats[kind * 64 + half * 32 + fr], v);
        }
    }
}

// ---------------------------------------------------------------------------
// Prep: cast x to bf16, build segment-major swizzled concat weights, zero stats.
// k-order: [x-taps (9*CIN_A, zero-padded to KSX*32) ; h-taps (576)].
// out[((ntile*KS+ks)*64+l)*8+j] = Wseg[k][n], n = ntile*16+(l&15),
// k = ks*32+((l>>4)&3)*8+j.
// ---------------------------------------------------------------------------
__device__ __forceinline__ ushort swz_elem_seg(
    const float* __restrict__ Wx, const float* __restrict__ Wh,
    int CIN_A, int idx)
{
    const int KX = 9 * CIN_A, KSX = (KX + 31) / 32, KS = KSX + 18;
    const int j = idx & 7, lw = (idx >> 3) & 63, rest = idx >> 9;
    const int ks = rest % KS, ntile = rest / KS;
    const int n = ntile * 16 + (lw & 15);
    const int k = ks * 32 + ((lw >> 4) & 3) * 8 + j;
    float v = 0.f;
    if (ks < KSX) {
        if (k < KX) {
            const int tap = k / CIN_A, ci = k % CIN_A;
            v = Wx[((size_t)tap * CIN_A + ci) * CO + n];
        }
    } else {
        const int kh = k - KSX * 32;                 // 0..575
        const int tap = kh >> 6, ci = kh & 63;
        v = Wh[((size_t)tap * 64 + ci) * CO + n];
    }
    return f2b(v);
}

__global__ __launch_bounds__(256) void prep_kernel(
    const float* __restrict__ x,
    const float* __restrict__ Wx1, const float* __restrict__ Wh1,
    const float* __restrict__ Wx2, const float* __restrict__ Wh2,
    ushort* __restrict__ xb, ushort* __restrict__ wc1, ushort* __restrict__ wc2,
    float* __restrict__ stats)
{
    constexpr int N0 = 368640;          // x: 2,949,120 elems / 8
    constexpr int N1 = 16 * 23 * 512;   // 188,416 (KS=5+18)
    constexpr int N2 = 16 * 36 * 512;   // 294,912 (KS=18+18)
    const int gid = blockIdx.x * 256 + threadIdx.x;
    if (gid < N0) {
        const float4 a = ((const float4*)x)[(size_t)gid * 2];
        const float4 b = ((const float4*)x)[(size_t)gid * 2 + 1];
        ushort o[8] = { f2b(a.x), f2b(a.y), f2b(a.z), f2b(a.w),
                        f2b(b.x), f2b(b.y), f2b(b.z), f2b(b.w) };
        *(uint4*)(xb + (size_t)gid * 8) = *(const uint4*)o;
    } else if (gid < N0 + N1) {
        wc1[gid - N0] = swz_elem_seg(Wx1, Wh1, 16, gid - N0);
    } else if (gid < N0 + N1 + N2) {
        wc2[gid - N0 - N1] = swz_elem_seg(Wx2, Wh2, 64, gid - N0 - N1);
    } else if (gid < N0 + N1 + N2 + 128) {
        stats[gid - N0 - N1 - N2] = 0.f;
    }
}

// ---------------------------------------------------------------------------
extern "C" void kernel_launch(void* const* d_in, const int* in_sizes, int n_in,
                              void* d_out, int out_size, void* d_ws, size_t ws_size,
                              hipStream_t stream)
{
    const float* x      = (const float*)d_in[0];
    const float* Wx1    = (const float*)d_in[1];
    const float* Wh1    = (const float*)d_in[2];
    const float* b1     = (const float*)d_in[3];
    const float* gamma1 = (const float*)d_in[4];
    const float* beta1  = (const float*)d_in[5];
    const float* Wx2    = (const float*)d_in[6];
    const float* Wh2    = (const float*)d_in[7];
    const float* b2     = (const float*)d_in[8];

    // workspace layout (bytes) -- ~49 MB of the 256 MB ws
    unsigned char* w = (unsigned char*)d_ws;
    ushort* seq1 = (ushort*)w;  w += 23592960;   // (T,B,2304,64) bf16
    ushort* xb   = (ushort*)w;  w += 5898240;    // (B,T,2304,16) bf16
    ushort* wc1  = (ushort*)w;  w += 376832;     // 16*23*512 u16
    ushort* wc2  = (ushort*)w;  w += 589824;     // 16*36*512 u16
    ushort* hb1a = (ushort*)w;  w += 2359296;
    ushort* hb1b = (ushort*)w;  w += 2359296;
    ushort* hb2a = (ushort*)w;  w += 2359296;
    ushort* hb2b = (ushort*)w;  w += 2359296;
    float*  c1   = (float*)w;   w += 4718592;
    float*  c2   = (float*)w;   w += 4718592;
    float*  stats = (float*)w;  w += 512;

    prep_kernel<<<3329, 256, 0, stream>>>(x, Wx1, Wh1, Wx2, Wh2, xb, wc1, wc2, stats);

    const long xStride = (long)T * IMGPIX * 16;
    ushort* hp1[2] = { hb1a, hb1b };

    // ----- layer 1 (STATS: accumulate BN sums; t=9 also writes d_out h1,c1) -----
    convlstm_step<16, 88, true, true, false, false><<<768, 256, 0, stream>>>(
        xb, xStride, hp1[0], wc1, b1, c1, hp1[1],
        seq1, stats, nullptr, nullptr, nullptr);
    for (int t = 1; t < 9; ++t)
        convlstm_step<16, 88, false, true, false, false><<<768, 256, 0, stream>>>(
            xb + (size_t)t * IMGPIX * 16, xStride, hp1[t & 1], wc1, b1, c1, hp1[(t + 1) & 1],
            seq1 + (size_t)t * STATE_ELEMS, stats, nullptr, nullptr, nullptr);
    convlstm_step<16, 88, false, true, false, true><<<768, 256, 0, stream>>>(
        xb + (size_t)9 * IMGPIX * 16, xStride, hp1[1], wc1, b1, c1, hp1[0],
        seq1 + (size_t)9 * STATE_ELEMS, stats, nullptr, nullptr, (float*)d_out);

    // ----- layer 2 (BNIN: normalize seq1 on the fly; t=9 writes d_out h2,c2) -----
    ushort* hp2[2] = { hb2a, hb2b };
    convlstm_step<64, 136, true, false, true, false><<<768, 256, 0, stream>>>(
        seq1, IMGPIX * 64, hp2[0], wc2, b2, c2, hp2[1],
        nullptr, stats, gamma1, beta1, nullptr);
    for (int t = 1; t < 9; ++t)
        convlstm_step<64, 136, false, false, true, false><<<768, 256, 0, stream>>>(
            seq1 + (size_t)t * STATE_ELEMS, IMGPIX * 64, hp2[t & 1], wc2, b2, c2, hp2[(t + 1) & 1],
            nullptr, stats, gamma1, beta1, nullptr);
    convlstm_step<64, 136, false, false, true, true><<<768, 256, 0, stream>>>(
        seq1 + (size_t)9 * STATE_ELEMS, IMGPIX * 64, hp2[1], wc2, b2, c2, hp2[0],
        nullptr, stats, gamma1, beta1, (float*)d_out + 2 * STATE_ELEMS);
}